// Round 6
// baseline (429.547 us; speedup 1.0000x reference)
//
#include <hip/hip_runtime.h>
#include <math.h>

#define N_NODES 50000
#define N_EDGES 800000
#define DF 128
#define EF 16
#define EH 64
#define NH 128
#define NC 40
#define NCP 64       // h2 padded columns (bf16)
#define SCAN_B 196   // ceil(50000/256)

typedef __attribute__((ext_vector_type(8))) short short8v;
typedef __attribute__((ext_vector_type(4))) short short4v;

__device__ __forceinline__ float bf2f(unsigned short u) {
    union { unsigned int i; float f; } c; c.i = ((unsigned int)u) << 16; return c.f;
}
__device__ __forceinline__ unsigned short f2bf(float f) {   // round-nearest-even
    union { float f; unsigned int i; } c; c.f = f;
    unsigned int r = c.i + 0x7FFFu + ((c.i >> 16) & 1u);
    return (unsigned short)(r >> 16);
}
__device__ __forceinline__ float rdlane(float v, int lane) {
    return __int_as_float(__builtin_amdgcn_readlane(__float_as_int(v), lane));
}

// ---------------------------------------------------------------- K1: edge MLP (+ fused dst-degree histogram)
__global__ __launch_bounds__(256) void edge_mlp_kernel(
    const float* __restrict__ ef, const float* __restrict__ W1,
    const float* __restrict__ b1, const float* __restrict__ W2,
    const float* __restrict__ b2, const int* __restrict__ dst,
    float* __restrict__ ew, int* __restrict__ deg)
{
    __shared__ float4 W1s4[EF * 16];   // [k][j4] view of W1[16][64]
    __shared__ float4 b1s4[16];
    __shared__ float4 W2s4[16];
    int t = threadIdx.x;
    for (int i = t; i < EF * 16; i += 256) W1s4[i] = ((const float4*)W1)[i];
    if (t < 16) { b1s4[t] = ((const float4*)b1)[t]; W2s4[t] = ((const float4*)W2)[t]; }
    __syncthreads();

    int e = blockIdx.x * 256 + t;
    if (e >= N_EDGES) return;

    float f[EF];
    const float4* ef4 = (const float4*)(ef + (long)e * EF);
    #pragma unroll
    for (int i = 0; i < 4; ++i) {
        float4 v = ef4[i];
        f[4*i+0] = v.x; f[4*i+1] = v.y; f[4*i+2] = v.z; f[4*i+3] = v.w;
    }
    float s = 0.f;
    #pragma unroll 4
    for (int jc = 0; jc < 16; ++jc) {
        float4 a = b1s4[jc];
        #pragma unroll
        for (int k = 0; k < EF; ++k) {
            float4 w = W1s4[k * 16 + jc];
            a.x += f[k] * w.x; a.y += f[k] * w.y;
            a.z += f[k] * w.z; a.w += f[k] * w.w;
        }
        float4 w2 = W2s4[jc];
        s += fmaxf(a.x, 0.f) * w2.x + fmaxf(a.y, 0.f) * w2.y
           + fmaxf(a.z, 0.f) * w2.z + fmaxf(a.w, 0.f) * w2.w;
    }
    s += b2[0];
    ew[e] = 1.f / (1.f + expf(-s));
    atomicAdd(&deg[dst[e]], 1);
}

// ---------------------------------------------------------------- K2: h = bf16(x @ Wc1)  (k-step-4, b128 LDS reads)
__global__ __launch_bounds__(256) void gemm1_kernel(
    const float* __restrict__ x, const float* __restrict__ Wc1,
    unsigned short* __restrict__ hb)
{
    __shared__ float xs[64][DF];   // 32 KB row-major; staging conflict-free
    int t = threadIdx.x;
    long r0 = (long)blockIdx.x * 64;
    for (int i = t; i < 64 * (DF / 4); i += 256) {    // float4 staging
        int r = i >> 5, kq = i & 31;
        long rr = r0 + r;
        float4 v = (rr < N_NODES) ? *(const float4*)(x + rr * DF + kq * 4)
                                  : make_float4(0.f, 0.f, 0.f, 0.f);
        *(float4*)(&xs[r][kq * 4]) = v;
    }
    __syncthreads();

    int tr = t >> 5;        // rows tr*8 .. +7
    int tc = t & 31;        // cols tc*4 .. +3
    float acc[8][4];
    #pragma unroll
    for (int i = 0; i < 8; ++i)
        #pragma unroll
        for (int j = 0; j < 4; ++j) acc[i][j] = 0.f;

    for (int k = 0; k < DF; k += 4) {
        float4 w0 = *(const float4*)(Wc1 + (k + 0) * NH + tc * 4);
        float4 w1 = *(const float4*)(Wc1 + (k + 1) * NH + tc * 4);
        float4 w2 = *(const float4*)(Wc1 + (k + 2) * NH + tc * 4);
        float4 w3 = *(const float4*)(Wc1 + (k + 3) * NH + tc * 4);
        #pragma unroll
        for (int i = 0; i < 8; ++i) {
            float4 xv = *(const float4*)(&xs[tr * 8 + i][k]);  // b128, 2-addr = free
            acc[i][0] += xv.x * w0.x + xv.y * w1.x + xv.z * w2.x + xv.w * w3.x;
            acc[i][1] += xv.x * w0.y + xv.y * w1.y + xv.z * w2.y + xv.w * w3.y;
            acc[i][2] += xv.x * w0.z + xv.y * w1.z + xv.z * w2.z + xv.w * w3.z;
            acc[i][3] += xv.x * w0.w + xv.y * w1.w + xv.z * w2.w + xv.w * w3.w;
        }
    }
    #pragma unroll
    for (int i = 0; i < 8; ++i) {
        long r = r0 + tr * 8 + i;
        if (r < N_NODES) {
            ushort4 sv;
            sv.x = f2bf(acc[i][0]); sv.y = f2bf(acc[i][1]);
            sv.z = f2bf(acc[i][2]); sv.w = f2bf(acc[i][3]);
            *(ushort4*)(hb + r * NH + tc * 4) = sv;
        }
    }
}

// ---------------------------------------------------------------- K3a/b/c: parallel exclusive scan deg -> rowptr
__global__ __launch_bounds__(256) void scan_part_kernel(
    const int* __restrict__ deg, int* __restrict__ bsum)
{
    __shared__ int red[256];
    int t = threadIdx.x;
    int n = blockIdx.x * 256 + t;
    red[t] = (n < N_NODES) ? deg[n] : 0;
    __syncthreads();
    for (int o = 128; o > 0; o >>= 1) {
        if (t < o) red[t] += red[t + o];
        __syncthreads();
    }
    if (t == 0) bsum[blockIdx.x] = red[0];
}

__global__ __launch_bounds__(256) void scan_top_kernel(
    const int* __restrict__ bsum, int* __restrict__ boff)
{
    __shared__ int s[256];
    int t = threadIdx.x;
    s[t] = (t < SCAN_B) ? bsum[t] : 0;
    __syncthreads();
    for (int o = 1; o < 256; o <<= 1) {
        int v = (t >= o) ? s[t - o] : 0;
        __syncthreads();
        s[t] += v;
        __syncthreads();
    }
    if (t < SCAN_B) boff[t] = (t == 0) ? 0 : s[t - 1];
}

__global__ __launch_bounds__(256) void scan_write_kernel(
    const int* __restrict__ deg, const int* __restrict__ boff,
    int* __restrict__ rowptr)
{
    __shared__ int s[256];
    int t = threadIdx.x;
    int n = blockIdx.x * 256 + t;
    int v = (n < N_NODES) ? deg[n] : 0;
    s[t] = v;
    __syncthreads();
    for (int o = 1; o < 256; o <<= 1) {
        int u = (t >= o) ? s[t - o] : 0;
        __syncthreads();
        s[t] += u;
        __syncthreads();
    }
    if (n < N_NODES) rowptr[n] = boff[blockIdx.x] + s[t] - v;
}

// ---------------------------------------------------------------- K4: CSR fill, payload packed as int2{src, ew-bits}
__global__ __launch_bounds__(256) void fill_csr_kernel(
    const int* __restrict__ dst, const int* __restrict__ src,
    const float* __restrict__ ew, int* __restrict__ rowptr,
    int2* __restrict__ csr)
{
    int e = blockIdx.x * 256 + threadIdx.x;
    if (e >= N_EDGES) return;
    int p = atomicAdd(&rowptr[dst[e]], 1);
    csr[p] = make_int2(src[e], __float_as_int(ew[e]));
}

// ---------------------------------------------------------------- K4b: Wc2T[c][k] = Wc2[k][c]  (40x128, 20KB)
__global__ __launch_bounds__(256) void wc2t_kernel(
    const float* __restrict__ Wc2, float* __restrict__ Wc2T)
{
    for (int i = threadIdx.x; i < NH * NC; i += 256) {
        int k = i / NC, c = i - k * NC;
        Wc2T[c * NH + k] = Wc2[i];
    }
}

// ---------------------------------------------------------------- K5: fused gather1 + gemm2 (1 wave = 1 node, no LDS)
// Wave = 4 groups x 16 lanes. Group g takes edge j*4+g; lane l16 loads h cols l16*8..+7 (bf16x8, 16B).
// gemm2 via readlane (h1 wave-uniform after reduce) + transposed Wc2 float4 loads — no DS-pipe traffic.
__global__ __launch_bounds__(256) void gather1_gemm2_kernel(
    const unsigned short* __restrict__ hb, const int* __restrict__ rp_end,
    const int2* __restrict__ csr, const float* __restrict__ bc1,
    const float* __restrict__ Wc2T, unsigned short* __restrict__ h2b)
{
    int t = threadIdx.x;
    int node = blockIdx.x * 4 + (t >> 6);   // grid 12500*4 = 50000 exact
    int lane = t & 63;
    int l16 = lane & 15, g = lane >> 4;

    int end   = rp_end[node];
    int start = (node == 0) ? 0 : rp_end[node - 1];

    float acc[8];
    #pragma unroll
    for (int i = 0; i < 8; ++i) acc[i] = 0.f;

    for (int base = start; base < end; base += 64) {
        int n = end - base; if (n > 64) n = 64;
        int s = 0; float w = 0.f;
        if (lane < n) {
            int2 p = csr[base + lane];
            s = p.x; w = __int_as_float(p.y);
        }
        #pragma unroll 4
        for (int j = 0; j * 4 < n; ++j) {
            int idx = j * 4 + g;                       // per-lane src lane
            int   sj = __shfl(s, idx, 64);
            float wj = __shfl(w, idx, 64);             // 0 beyond n -> no contribution
            short8v hv = *(const short8v*)(hb + (long)sj * NH + l16 * 8);
            #pragma unroll
            for (int i = 0; i < 8; ++i)
                acc[i] += wj * bf2f((unsigned short)hv[i]);
        }
    }
    // sum the 4 groups' disjoint edge sets -> acc identical across all 4 groups
    #pragma unroll
    for (int i = 0; i < 8; ++i) {
        acc[i] += __shfl_xor(acc[i], 16, 64);
        acc[i] += __shfl_xor(acc[i], 32, 64);
    }
    // bias + relu -> h1 cols l16*8+i (replicated across groups, wave-uniform per l16)
    float4 b0 = *(const float4*)(bc1 + l16 * 8);
    float4 b1 = *(const float4*)(bc1 + l16 * 8 + 4);
    float h1v[8];
    h1v[0] = fmaxf(acc[0] + b0.x, 0.f); h1v[1] = fmaxf(acc[1] + b0.y, 0.f);
    h1v[2] = fmaxf(acc[2] + b0.z, 0.f); h1v[3] = fmaxf(acc[3] + b0.w, 0.f);
    h1v[4] = fmaxf(acc[4] + b1.x, 0.f); h1v[5] = fmaxf(acc[5] + b1.y, 0.f);
    h1v[6] = fmaxf(acc[6] + b1.z, 0.f); h1v[7] = fmaxf(acc[7] + b1.w, 0.f);

    // gemm2: o[c] = sum_k h1[k] * Wc2[k][c].  h1[k] lives at lane k>>3, elem k&7 (uniform
    // across groups) -> v_readlane (VALU, no DS pipe). Wc2T row c read as float4 (L1-hot).
    int c = (lane < NC) ? lane : (NC - 1);
    const float4* wrow = (const float4*)(Wc2T + c * NH);
    float o = 0.f;
    #pragma unroll
    for (int kq = 0; kq < 32; ++kq) {       // k = kq*4 .. +3, all from lane kq>>1
        float4 wv = wrow[kq];
        // fully unrolled -> literal lane/elem indices (no scratch)
        if ((kq & 1) == 0) {
            o += rdlane(h1v[0], kq >> 1) * wv.x + rdlane(h1v[1], kq >> 1) * wv.y
               + rdlane(h1v[2], kq >> 1) * wv.z + rdlane(h1v[3], kq >> 1) * wv.w;
        } else {
            o += rdlane(h1v[4], kq >> 1) * wv.x + rdlane(h1v[5], kq >> 1) * wv.y
               + rdlane(h1v[6], kq >> 1) * wv.z + rdlane(h1v[7], kq >> 1) * wv.w;
        }
    }
    h2b[(long)node * NCP + lane] = f2bf((lane < NC) ? o : 0.f);  // 128B coalesced
}

// ---------------------------------------------------------------- K6: gather2 + bias + (-log_softmax) (1 wave = 1 node)
__global__ __launch_bounds__(256) void gather2_lsm_kernel(
    const unsigned short* __restrict__ h2b, const int* __restrict__ rp_end,
    const int2* __restrict__ csr, const float* __restrict__ bc2,
    float* __restrict__ out)
{
    int t = threadIdx.x;
    int node = blockIdx.x * 4 + (t >> 6);
    int lane = t & 63;
    int l16 = lane & 15, g = lane >> 4;

    int end   = rp_end[node];
    int start = (node == 0) ? 0 : rp_end[node - 1];

    float acc[4];
    #pragma unroll
    for (int i = 0; i < 4; ++i) acc[i] = 0.f;

    for (int base = start; base < end; base += 64) {
        int n = end - base; if (n > 64) n = 64;
        int s = 0; float w = 0.f;
        if (lane < n) {
            int2 p = csr[base + lane];
            s = p.x; w = __int_as_float(p.y);
        }
        #pragma unroll 4
        for (int j = 0; j * 4 < n; ++j) {
            int idx = j * 4 + g;
            int   sj = __shfl(s, idx, 64);
            float wj = __shfl(w, idx, 64);
            short4v hv = *(const short4v*)(h2b + (long)sj * NCP + l16 * 4);
            #pragma unroll
            for (int i = 0; i < 4; ++i)
                acc[i] += wj * bf2f((unsigned short)hv[i]);
        }
    }
    #pragma unroll
    for (int i = 0; i < 4; ++i) {
        acc[i] += __shfl_xor(acc[i], 16, 64);
        acc[i] += __shfl_xor(acc[i], 32, 64);
    }

    // bias + masked log-softmax over cols l16*4+i (valid iff l16 < 10)
    bool valid = (l16 < 10);
    float4 bcv = valid ? *(const float4*)(bc2 + l16 * 4) : make_float4(0.f, 0.f, 0.f, 0.f);
    float v[4];
    v[0] = acc[0] + bcv.x; v[1] = acc[1] + bcv.y;
    v[2] = acc[2] + bcv.z; v[3] = acc[3] + bcv.w;

    float mx = valid ? fmaxf(fmaxf(v[0], v[1]), fmaxf(v[2], v[3])) : -INFINITY;
    #pragma unroll
    for (int o = 1; o <= 8; o <<= 1) mx = fmaxf(mx, __shfl_xor(mx, o, 64));
    float se = 0.f;
    if (valid) se = expf(v[0]-mx) + expf(v[1]-mx) + expf(v[2]-mx) + expf(v[3]-mx);
    #pragma unroll
    for (int o = 1; o <= 8; o <<= 1) se += __shfl_xor(se, o, 64);
    float lse = mx + logf(se);

    if (valid && g == 0) {
        float4 r = make_float4(lse - v[0], lse - v[1], lse - v[2], lse - v[3]);
        *(float4*)(out + (long)node * NC + l16 * 4) = r;   // 160B/row, 16B aligned
    }
}

// ----------------------------------------------------------------
extern "C" void kernel_launch(void* const* d_in, const int* in_sizes, int n_in,
                              void* d_out, int out_size, void* d_ws, size_t ws_size,
                              hipStream_t stream)
{
    const float* x         = (const float*)d_in[0];
    const float* edge_feat = (const float*)d_in[1];
    const float* W1        = (const float*)d_in[2];
    const float* b1        = (const float*)d_in[3];
    const float* W2        = (const float*)d_in[4];
    const float* b2        = (const float*)d_in[5];
    const float* Wc1       = (const float*)d_in[6];
    const float* bc1       = (const float*)d_in[7];
    const float* Wc2       = (const float*)d_in[8];
    const float* bc2       = (const float*)d_in[9];
    const int*   eidx      = (const int*)d_in[10];
    const int*   dst = eidx;             // edge_index[0] (aggregation target)
    const int*   src = eidx + N_EDGES;   // edge_index[1]
    float* out = (float*)d_out;

    // ws layout: ew | hb(bf16) | h2b(bf16,pad64) | csr(int2) | deg | rowptr | bsum | boff | Wc2T
    float*          ew     = (float*)d_ws;                       // E        3.2 MB
    unsigned short* hb     = (unsigned short*)(ew + N_EDGES);    // N*NH*2  12.8 MB
    unsigned short* h2b    = hb + (long)N_NODES * NH;            // N*64*2   6.4 MB
    int2*           csr    = (int2*)(h2b + (long)N_NODES * NCP); // E*8      6.4 MB
    int*            deg    = (int*)(csr + N_EDGES);              // N        0.2 MB
    int*            rowptr = deg + N_NODES;                      // N        0.2 MB
    int*            bsum   = rowptr + N_NODES;                   // 256
    int*            boff   = bsum + 256;                         // 256
    float*          Wc2T   = (float*)(boff + 256);               // 40*128  20 KB

    hipMemsetAsync(deg, 0, sizeof(int) * (size_t)N_NODES, stream);

    edge_mlp_kernel<<<(N_EDGES + 255) / 256, 256, 0, stream>>>(
        edge_feat, W1, b1, W2, b2, dst, ew, deg);
    gemm1_kernel<<<(N_NODES + 63) / 64, 256, 0, stream>>>(x, Wc1, hb);
    scan_part_kernel<<<SCAN_B, 256, 0, stream>>>(deg, bsum);
    scan_top_kernel<<<1, 256, 0, stream>>>(bsum, boff);
    scan_write_kernel<<<SCAN_B, 256, 0, stream>>>(deg, boff, rowptr);
    wc2t_kernel<<<1, 256, 0, stream>>>(Wc2, Wc2T);
    fill_csr_kernel<<<(N_EDGES + 255) / 256, 256, 0, stream>>>(
        dst, src, ew, rowptr, csr);
    gather1_gemm2_kernel<<<N_NODES / 4, 256, 0, stream>>>(
        hb, rowptr, csr, bc1, Wc2T, h2b);
    gather2_lsm_kernel<<<N_NODES / 4, 256, 0, stream>>>(
        h2b, rowptr, csr, bc2, out);
}

// Round 8
// 350.507 us; speedup vs baseline: 1.2255x; 1.2255x over previous
//
#include <hip/hip_runtime.h>
#include <math.h>

#define N_NODES 50000
#define N_EDGES 800000
#define DF 128
#define EF 16
#define EH 64
#define NH 128
#define NC 40
#define NCP 64       // h2 padded columns (bf16)
#define SCAN_B 196   // ceil(50000/256)

typedef __attribute__((ext_vector_type(8))) short short8v;
typedef __attribute__((ext_vector_type(4))) short short4v;
typedef __attribute__((ext_vector_type(4))) float f32x4;

__device__ __forceinline__ float bf2f(unsigned short u) {
    union { unsigned int i; float f; } c; c.i = ((unsigned int)u) << 16; return c.f;
}
__device__ __forceinline__ unsigned short f2bf(float f) {   // round-nearest-even
    union { float f; unsigned int i; } c; c.f = f;
    unsigned int r = c.i + 0x7FFFu + ((c.i >> 16) & 1u);
    return (unsigned short)(r >> 16);
}

// ---------------------------------------------------------------- K1: edge MLP via MFMA (+ fused dst-degree histogram)
// ew[e] = sigmoid( relu(ef[e]@W1 + b1) @ W2 + b2 ).  Wave = 64 edges = 4 row-tiles of 16.
// MFMA 16x16x32 bf16, K padded 16->32 with zeros. B/b1/W2 frags live in registers for the wave.
__global__ __launch_bounds__(256) void edge_mlp_kernel(
    const float* __restrict__ ef, const float* __restrict__ W1,
    const float* __restrict__ b1, const float* __restrict__ W2,
    const float* __restrict__ b2, const int* __restrict__ dst,
    float* __restrict__ ew, int* __restrict__ deg)
{
    int t = threadIdx.x;
    int lane = t & 63;
    int wv = t >> 6;
    int l15 = lane & 15, kg = lane >> 4;        // kgroup 0..3 (k = kg*8 + i)

    // B-frag for col-tile tt: lane holds W1[kg*8+i][16*tt+l15], zero for k>=16
    short8v Bf[4];
    float b1v[4], w2v[4];
    #pragma unroll
    for (int tt = 0; tt < 4; ++tt) {
        int col = tt * 16 + l15;
        short8v bv = {0, 0, 0, 0, 0, 0, 0, 0};
        if (kg < 2) {
            #pragma unroll
            for (int i = 0; i < 8; ++i)
                bv[i] = (short)f2bf(W1[(kg * 8 + i) * EH + col]);
        }
        Bf[tt] = bv;
        b1v[tt] = b1[col];
        w2v[tt] = W2[col];
    }
    float b2s = b2[0];

    long e0w = ((long)blockIdx.x * 4 + wv) * 64;   // 3125 blocks * 256 = 800000 exact

    #pragma unroll
    for (int rt = 0; rt < 4; ++rt) {
        long e0 = e0w + rt * 16;
        // A-frag: lane holds ef[e0+l15][kg*8+i] (fp32->bf16); kg>=2 -> zero (K pad)
        short8v Af = {0, 0, 0, 0, 0, 0, 0, 0};
        if (kg < 2) {
            const float4* p = (const float4*)(ef + (e0 + l15) * EF + kg * 8);
            float4 v0 = p[0], v1 = p[1];
            Af[0] = (short)f2bf(v0.x); Af[1] = (short)f2bf(v0.y);
            Af[2] = (short)f2bf(v0.z); Af[3] = (short)f2bf(v0.w);
            Af[4] = (short)f2bf(v1.x); Af[5] = (short)f2bf(v1.y);
            Af[6] = (short)f2bf(v1.z); Af[7] = (short)f2bf(v1.w);
        }
        f32x4 a0 = {0.f, 0.f, 0.f, 0.f}, a1 = a0, a2 = a0, a3 = a0;
        a0 = __builtin_amdgcn_mfma_f32_16x16x32_bf16(Af, Bf[0], a0, 0, 0, 0);
        a1 = __builtin_amdgcn_mfma_f32_16x16x32_bf16(Af, Bf[1], a1, 0, 0, 0);
        a2 = __builtin_amdgcn_mfma_f32_16x16x32_bf16(Af, Bf[2], a2, 0, 0, 0);
        a3 = __builtin_amdgcn_mfma_f32_16x16x32_bf16(Af, Bf[3], a3, 0, 0, 0);

        // layer 2: s_r = sum_t relu(acc_t[r] + b1v[t]) * w2v[t]; edge = kg*4 + r, j = l15+16t
        float s[4];
        #pragma unroll
        for (int r = 0; r < 4; ++r) {
            s[r] = fmaxf(a0[r] + b1v[0], 0.f) * w2v[0]
                 + fmaxf(a1[r] + b1v[1], 0.f) * w2v[1]
                 + fmaxf(a2[r] + b1v[2], 0.f) * w2v[2]
                 + fmaxf(a3[r] + b1v[3], 0.f) * w2v[3];
            // reduce over the 16 lanes of this kgroup (j dimension)
            s[r] += __shfl_xor(s[r], 1, 64);
            s[r] += __shfl_xor(s[r], 2, 64);
            s[r] += __shfl_xor(s[r], 4, 64);
            s[r] += __shfl_xor(s[r], 8, 64);
        }
        // group kg holds edges e0 + kg*4 + r; lane l15==0 writes float4 (coalesced 64B/wave)
        if (l15 == 0) {
            float4 sg;
            sg.x = 1.f / (1.f + expf(-(s[0] + b2s)));
            sg.y = 1.f / (1.f + expf(-(s[1] + b2s)));
            sg.z = 1.f / (1.f + expf(-(s[2] + b2s)));
            sg.w = 1.f / (1.f + expf(-(s[3] + b2s)));
            *(float4*)(ew + e0 + kg * 4) = sg;
        }
    }
    atomicAdd(&deg[dst[e0w + lane]], 1);   // one edge per lane, coalesced dst read
}

// ---------------------------------------------------------------- K2: h = bf16(x @ Wc1)  (k-step-4, b128 LDS reads)
__global__ __launch_bounds__(256) void gemm1_kernel(
    const float* __restrict__ x, const float* __restrict__ Wc1,
    unsigned short* __restrict__ hb)
{
    __shared__ float xs[64][DF];   // 32 KB row-major; staging conflict-free
    int t = threadIdx.x;
    long r0 = (long)blockIdx.x * 64;
    for (int i = t; i < 64 * (DF / 4); i += 256) {    // float4 staging
        int r = i >> 5, kq = i & 31;
        long rr = r0 + r;
        float4 v = (rr < N_NODES) ? *(const float4*)(x + rr * DF + kq * 4)
                                  : make_float4(0.f, 0.f, 0.f, 0.f);
        *(float4*)(&xs[r][kq * 4]) = v;
    }
    __syncthreads();

    int tr = t >> 5;        // rows tr*8 .. +7
    int tc = t & 31;        // cols tc*4 .. +3
    float acc[8][4];
    #pragma unroll
    for (int i = 0; i < 8; ++i)
        #pragma unroll
        for (int j = 0; j < 4; ++j) acc[i][j] = 0.f;

    for (int k = 0; k < DF; k += 4) {
        float4 w0 = *(const float4*)(Wc1 + (k + 0) * NH + tc * 4);
        float4 w1 = *(const float4*)(Wc1 + (k + 1) * NH + tc * 4);
        float4 w2 = *(const float4*)(Wc1 + (k + 2) * NH + tc * 4);
        float4 w3 = *(const float4*)(Wc1 + (k + 3) * NH + tc * 4);
        #pragma unroll
        for (int i = 0; i < 8; ++i) {
            float4 xv = *(const float4*)(&xs[tr * 8 + i][k]);  // b128, 2-addr = free
            acc[i][0] += xv.x * w0.x + xv.y * w1.x + xv.z * w2.x + xv.w * w3.x;
            acc[i][1] += xv.x * w0.y + xv.y * w1.y + xv.z * w2.y + xv.w * w3.y;
            acc[i][2] += xv.x * w0.z + xv.y * w1.z + xv.z * w2.z + xv.w * w3.z;
            acc[i][3] += xv.x * w0.w + xv.y * w1.w + xv.z * w2.w + xv.w * w3.w;
        }
    }
    #pragma unroll
    for (int i = 0; i < 8; ++i) {
        long r = r0 + tr * 8 + i;
        if (r < N_NODES) {
            ushort4 sv;
            sv.x = f2bf(acc[i][0]); sv.y = f2bf(acc[i][1]);
            sv.z = f2bf(acc[i][2]); sv.w = f2bf(acc[i][3]);
            *(ushort4*)(hb + r * NH + tc * 4) = sv;
        }
    }
}

// ---------------------------------------------------------------- K3a/b/c: parallel exclusive scan deg -> rowptr
__global__ __launch_bounds__(256) void scan_part_kernel(
    const int* __restrict__ deg, int* __restrict__ bsum)
{
    __shared__ int red[256];
    int t = threadIdx.x;
    int n = blockIdx.x * 256 + t;
    red[t] = (n < N_NODES) ? deg[n] : 0;
    __syncthreads();
    for (int o = 128; o > 0; o >>= 1) {
        if (t < o) red[t] += red[t + o];
        __syncthreads();
    }
    if (t == 0) bsum[blockIdx.x] = red[0];
}

__global__ __launch_bounds__(256) void scan_top_kernel(
    const int* __restrict__ bsum, int* __restrict__ boff)
{
    __shared__ int s[256];
    int t = threadIdx.x;
    s[t] = (t < SCAN_B) ? bsum[t] : 0;
    __syncthreads();
    for (int o = 1; o < 256; o <<= 1) {
        int v = (t >= o) ? s[t - o] : 0;
        __syncthreads();
        s[t] += v;
        __syncthreads();
    }
    if (t < SCAN_B) boff[t] = (t == 0) ? 0 : s[t - 1];
}

__global__ __launch_bounds__(256) void scan_write_kernel(
    const int* __restrict__ deg, const int* __restrict__ boff,
    int* __restrict__ rowptr)
{
    __shared__ int s[256];
    int t = threadIdx.x;
    int n = blockIdx.x * 256 + t;
    int v = (n < N_NODES) ? deg[n] : 0;
    s[t] = v;
    __syncthreads();
    for (int o = 1; o < 256; o <<= 1) {
        int u = (t >= o) ? s[t - o] : 0;
        __syncthreads();
        s[t] += u;
        __syncthreads();
    }
    if (n < N_NODES) rowptr[n] = boff[blockIdx.x] + s[t] - v;
}

// ---------------------------------------------------------------- K4: CSR fill, payload packed as int2{src, ew-bits}
__global__ __launch_bounds__(256) void fill_csr_kernel(
    const int* __restrict__ dst, const int* __restrict__ src,
    const float* __restrict__ ew, int* __restrict__ rowptr,
    int2* __restrict__ csr)
{
    int e = blockIdx.x * 256 + threadIdx.x;
    if (e >= N_EDGES) return;
    int p = atomicAdd(&rowptr[dst[e]], 1);
    csr[p] = make_int2(src[e], __float_as_int(ew[e]));
}

// ---------------------------------------------------------------- K5: fused gather1 + gemm2 (1 wave = 1 node, no LDS)
// Wave = 4 groups x 16 lanes. Group g takes edge j*4+g; lane l16 loads h cols l16*8..+7 (bf16x8, 16B).
__global__ __launch_bounds__(256) void gather1_gemm2_kernel(
    const unsigned short* __restrict__ hb, const int* __restrict__ rp_end,
    const int2* __restrict__ csr, const float* __restrict__ bc1,
    const float* __restrict__ Wc2, unsigned short* __restrict__ h2b)
{
    int t = threadIdx.x;
    int node = blockIdx.x * 4 + (t >> 6);   // grid 12500*4 = 50000 exact
    int lane = t & 63;
    int l16 = lane & 15, g = lane >> 4;

    int end   = rp_end[node];
    int start = (node == 0) ? 0 : rp_end[node - 1];

    float acc[8];
    #pragma unroll
    for (int i = 0; i < 8; ++i) acc[i] = 0.f;

    for (int base = start; base < end; base += 64) {
        int n = end - base; if (n > 64) n = 64;
        int s = 0; float w = 0.f;
        if (lane < n) {
            int2 p = csr[base + lane];
            s = p.x; w = __int_as_float(p.y);
        }
        #pragma unroll 4
        for (int j = 0; j * 4 < n; ++j) {
            int idx = j * 4 + g;                       // per-lane src lane
            int   sj = __shfl(s, idx, 64);
            float wj = __shfl(w, idx, 64);             // 0 beyond n -> no contribution
            short8v hv = *(const short8v*)(hb + (long)sj * NH + l16 * 8);
            #pragma unroll
            for (int i = 0; i < 8; ++i)
                acc[i] += wj * bf2f((unsigned short)hv[i]);
        }
    }
    // sum the 4 groups' disjoint edge sets -> acc identical across all 4 groups
    #pragma unroll
    for (int i = 0; i < 8; ++i) {
        acc[i] += __shfl_xor(acc[i], 16, 64);
        acc[i] += __shfl_xor(acc[i], 32, 64);
    }
    // bias + relu -> h1 cols l16*8+i (replicated across groups)
    float4 b0 = *(const float4*)(bc1 + l16 * 8);
    float4 b1 = *(const float4*)(bc1 + l16 * 8 + 4);
    float h1v[8];
    h1v[0] = fmaxf(acc[0] + b0.x, 0.f); h1v[1] = fmaxf(acc[1] + b0.y, 0.f);
    h1v[2] = fmaxf(acc[2] + b0.z, 0.f); h1v[3] = fmaxf(acc[3] + b0.w, 0.f);
    h1v[4] = fmaxf(acc[4] + b1.x, 0.f); h1v[5] = fmaxf(acc[5] + b1.y, 0.f);
    h1v[6] = fmaxf(acc[6] + b1.z, 0.f); h1v[7] = fmaxf(acc[7] + b1.w, 0.f);

    // gemm2 in registers: h1[k] lives in lane (k>>3), elem (k&7). Wc2 is L1-resident.
    int c = (lane < NC) ? lane : (NC - 1);
    float o = 0.f;
    #pragma unroll 8
    for (int k = 0; k < NH; ++k) {
        float hk = __shfl(h1v[k & 7], k >> 3, 64);     // uniform src lane -> broadcast
        o += hk * Wc2[k * NC + c];
    }
    h2b[(long)node * NCP + lane] = f2bf((lane < NC) ? o : 0.f);  // 128B coalesced
}

// ---------------------------------------------------------------- K6: gather2 + bias + (-log_softmax) (1 wave = 1 node)
__global__ __launch_bounds__(256) void gather2_lsm_kernel(
    const unsigned short* __restrict__ h2b, const int* __restrict__ rp_end,
    const int2* __restrict__ csr, const float* __restrict__ bc2,
    float* __restrict__ out)
{
    int t = threadIdx.x;
    int node = blockIdx.x * 4 + (t >> 6);
    int lane = t & 63;
    int l16 = lane & 15, g = lane >> 4;

    int end   = rp_end[node];
    int start = (node == 0) ? 0 : rp_end[node - 1];

    float acc[4];
    #pragma unroll
    for (int i = 0; i < 4; ++i) acc[i] = 0.f;

    for (int base = start; base < end; base += 64) {
        int n = end - base; if (n > 64) n = 64;
        int s = 0; float w = 0.f;
        if (lane < n) {
            int2 p = csr[base + lane];
            s = p.x; w = __int_as_float(p.y);
        }
        #pragma unroll 4
        for (int j = 0; j * 4 < n; ++j) {
            int idx = j * 4 + g;
            int   sj = __shfl(s, idx, 64);
            float wj = __shfl(w, idx, 64);
            short4v hv = *(const short4v*)(h2b + (long)sj * NCP + l16 * 4);
            #pragma unroll
            for (int i = 0; i < 4; ++i)
                acc[i] += wj * bf2f((unsigned short)hv[i]);
        }
    }
    #pragma unroll
    for (int i = 0; i < 4; ++i) {
        acc[i] += __shfl_xor(acc[i], 16, 64);
        acc[i] += __shfl_xor(acc[i], 32, 64);
    }

    // bias + masked log-softmax over cols l16*4+i (valid iff l16 < 10)
    bool valid = (l16 < 10);
    float4 bcv = valid ? *(const float4*)(bc2 + l16 * 4) : make_float4(0.f, 0.f, 0.f, 0.f);
    float v[4];
    v[0] = acc[0] + bcv.x; v[1] = acc[1] + bcv.y;
    v[2] = acc[2] + bcv.z; v[3] = acc[3] + bcv.w;

    float mx = valid ? fmaxf(fmaxf(v[0], v[1]), fmaxf(v[2], v[3])) : -INFINITY;
    #pragma unroll
    for (int o = 1; o <= 8; o <<= 1) mx = fmaxf(mx, __shfl_xor(mx, o, 64));
    float se = 0.f;
    if (valid) se = expf(v[0]-mx) + expf(v[1]-mx) + expf(v[2]-mx) + expf(v[3]-mx);
    #pragma unroll
    for (int o = 1; o <= 8; o <<= 1) se += __shfl_xor(se, o, 64);
    float lse = mx + logf(se);

    if (valid && g == 0) {
        float4 r = make_float4(lse - v[0], lse - v[1], lse - v[2], lse - v[3]);
        *(float4*)(out + (long)node * NC + l16 * 4) = r;   // 160B/row, 16B aligned
    }
}

// ----------------------------------------------------------------
extern "C" void kernel_launch(void* const* d_in, const int* in_sizes, int n_in,
                              void* d_out, int out_size, void* d_ws, size_t ws_size,
                              hipStream_t stream)
{
    const float* x         = (const float*)d_in[0];
    const float* edge_feat = (const float*)d_in[1];
    const float* W1        = (const float*)d_in[2];
    const float* b1        = (const float*)d_in[3];
    const float* W2        = (const float*)d_in[4];
    const float* b2        = (const float*)d_in[5];
    const float* Wc1       = (const float*)d_in[6];
    const float* bc1       = (const float*)d_in[7];
    const float* Wc2       = (const float*)d_in[8];
    const float* bc2       = (const float*)d_in[9];
    const int*   eidx      = (const int*)d_in[10];
    const int*   dst = eidx;             // edge_index[0] (aggregation target)
    const int*   src = eidx + N_EDGES;   // edge_index[1]
    float* out = (float*)d_out;

    // ws layout: ew | hb(bf16) | h2b(bf16,pad64) | csr(int2) | deg | rowptr | bsum | boff
    float*          ew     = (float*)d_ws;                       // E        3.2 MB
    unsigned short* hb     = (unsigned short*)(ew + N_EDGES);    // N*NH*2  12.8 MB
    unsigned short* h2b    = hb + (long)N_NODES * NH;            // N*64*2   6.4 MB
    int2*           csr    = (int2*)(h2b + (long)N_NODES * NCP); // E*8      6.4 MB
    int*            deg    = (int*)(csr + N_EDGES);              // N        0.2 MB
    int*            rowptr = deg + N_NODES;                      // N        0.2 MB
    int*            bsum   = rowptr + N_NODES;                   // 256
    int*            boff   = bsum + 256;                         // 256

    hipMemsetAsync(deg, 0, sizeof(int) * (size_t)N_NODES, stream);

    edge_mlp_kernel<<<N_EDGES / 256, 256, 0, stream>>>(
        edge_feat, W1, b1, W2, b2, dst, ew, deg);
    gemm1_kernel<<<(N_NODES + 63) / 64, 256, 0, stream>>>(x, Wc1, hb);
    scan_part_kernel<<<SCAN_B, 256, 0, stream>>>(deg, bsum);
    scan_top_kernel<<<1, 256, 0, stream>>>(bsum, boff);
    scan_write_kernel<<<SCAN_B, 256, 0, stream>>>(deg, boff, rowptr);
    fill_csr_kernel<<<(N_EDGES + 255) / 256, 256, 0, stream>>>(
        dst, src, ew, rowptr, csr);
    gather1_gemm2_kernel<<<N_NODES / 4, 256, 0, stream>>>(
        hb, rowptr, csr, bc1, Wc2, h2b);
    gather2_lsm_kernel<<<N_NODES / 4, 256, 0, stream>>>(
        h2b, rowptr, csr, bc2, out);
}

// Round 9
// 346.277 us; speedup vs baseline: 1.2405x; 1.0122x over previous
//
#include <hip/hip_runtime.h>
#include <math.h>

#define N_NODES 50000
#define N_EDGES 800000
#define DF 128
#define EF 16
#define EH 64
#define NH 128
#define NC 40
#define SCAN_B 196   // ceil(50000/256)

typedef __attribute__((ext_vector_type(8))) short short8v;
typedef __attribute__((ext_vector_type(4))) short short4v;
typedef __attribute__((ext_vector_type(4))) float f32x4;

__device__ __forceinline__ float bf2f(unsigned short u) {
    union { unsigned int i; float f; } c; c.i = ((unsigned int)u) << 16; return c.f;
}
__device__ __forceinline__ unsigned short f2bf(float f) {   // round-nearest-even
    union { float f; unsigned int i; } c; c.f = f;
    unsigned int r = c.i + 0x7FFFu + ((c.i >> 16) & 1u);
    return (unsigned short)(r >> 16);
}

// ---------------------------------------------------------------- K1: edge MLP via MFMA (+ fused dst-degree histogram)
// ew[e] = sigmoid( relu(ef[e]@W1 + b1) @ W2 + b2 ).  Wave = 64 edges = 4 row-tiles of 16.
__global__ __launch_bounds__(256) void edge_mlp_kernel(
    const float* __restrict__ ef, const float* __restrict__ W1,
    const float* __restrict__ b1, const float* __restrict__ W2,
    const float* __restrict__ b2, const int* __restrict__ dst,
    float* __restrict__ ew, int* __restrict__ deg)
{
    int t = threadIdx.x;
    int lane = t & 63;
    int wv = t >> 6;
    int l15 = lane & 15, kg = lane >> 4;        // kgroup 0..3 (k = kg*8 + i)

    // B-frag for col-tile tt: lane holds W1[kg*8+i][16*tt+l15], zero for k>=16
    short8v Bf[4];
    float b1v[4], w2v[4];
    #pragma unroll
    for (int tt = 0; tt < 4; ++tt) {
        int col = tt * 16 + l15;
        short8v bv = {0, 0, 0, 0, 0, 0, 0, 0};
        if (kg < 2) {
            #pragma unroll
            for (int i = 0; i < 8; ++i)
                bv[i] = (short)f2bf(W1[(kg * 8 + i) * EH + col]);
        }
        Bf[tt] = bv;
        b1v[tt] = b1[col];
        w2v[tt] = W2[col];
    }
    float b2s = b2[0];

    long e0w = ((long)blockIdx.x * 4 + wv) * 64;   // 3125 blocks * 256 = 800000 exact

    #pragma unroll
    for (int rt = 0; rt < 4; ++rt) {
        long e0 = e0w + rt * 16;
        short8v Af = {0, 0, 0, 0, 0, 0, 0, 0};
        if (kg < 2) {
            const float4* p = (const float4*)(ef + (e0 + l15) * EF + kg * 8);
            float4 v0 = p[0], v1 = p[1];
            Af[0] = (short)f2bf(v0.x); Af[1] = (short)f2bf(v0.y);
            Af[2] = (short)f2bf(v0.z); Af[3] = (short)f2bf(v0.w);
            Af[4] = (short)f2bf(v1.x); Af[5] = (short)f2bf(v1.y);
            Af[6] = (short)f2bf(v1.z); Af[7] = (short)f2bf(v1.w);
        }
        f32x4 a0 = {0.f, 0.f, 0.f, 0.f}, a1 = a0, a2 = a0, a3 = a0;
        a0 = __builtin_amdgcn_mfma_f32_16x16x32_bf16(Af, Bf[0], a0, 0, 0, 0);
        a1 = __builtin_amdgcn_mfma_f32_16x16x32_bf16(Af, Bf[1], a1, 0, 0, 0);
        a2 = __builtin_amdgcn_mfma_f32_16x16x32_bf16(Af, Bf[2], a2, 0, 0, 0);
        a3 = __builtin_amdgcn_mfma_f32_16x16x32_bf16(Af, Bf[3], a3, 0, 0, 0);

        float s[4];
        #pragma unroll
        for (int r = 0; r < 4; ++r) {
            s[r] = fmaxf(a0[r] + b1v[0], 0.f) * w2v[0]
                 + fmaxf(a1[r] + b1v[1], 0.f) * w2v[1]
                 + fmaxf(a2[r] + b1v[2], 0.f) * w2v[2]
                 + fmaxf(a3[r] + b1v[3], 0.f) * w2v[3];
            s[r] += __shfl_xor(s[r], 1, 64);
            s[r] += __shfl_xor(s[r], 2, 64);
            s[r] += __shfl_xor(s[r], 4, 64);
            s[r] += __shfl_xor(s[r], 8, 64);
        }
        if (l15 == 0) {
            float4 sg;
            sg.x = 1.f / (1.f + expf(-(s[0] + b2s)));
            sg.y = 1.f / (1.f + expf(-(s[1] + b2s)));
            sg.z = 1.f / (1.f + expf(-(s[2] + b2s)));
            sg.w = 1.f / (1.f + expf(-(s[3] + b2s)));
            *(float4*)(ew + e0 + kg * 4) = sg;
        }
    }
    atomicAdd(&deg[dst[e0w + lane]], 1);
}

// ---------------------------------------------------------------- K1b: Wc1T (bf16, transposed) prep: Wc1T[c][k] = bf16(Wc1[k][c])
__global__ __launch_bounds__(256) void wc1t_kernel(
    const float* __restrict__ Wc1, unsigned short* __restrict__ Wc1T)
{
    int i = blockIdx.x * 256 + threadIdx.x;   // 64 blocks x 256 = 16384
    int c = i >> 7, k = i & 127;
    Wc1T[i] = f2bf(Wc1[k * NH + c]);          // writes contiguous
}

// ---------------------------------------------------------------- K2: h = bf16(x @ Wc1) via MFMA, no LDS
// Wave = 16 rows x 128 cols. A-frags loaded once (reused over 8 col-tiles); B from Wc1T (L1/L2-hot).
__global__ __launch_bounds__(256) void gemm1_kernel(
    const float* __restrict__ x, const unsigned short* __restrict__ Wc1T,
    unsigned short* __restrict__ hb)
{
    int t = threadIdx.x;
    int lane = t & 63, wv = t >> 6;
    int l15 = lane & 15, kg = lane >> 4;
    long r0w = ((long)blockIdx.x * 4 + wv) * 16;
    long arow = r0w + l15;
    bool aok = (arow < N_NODES);

    // A-frag per k-step: lane holds x[r0w+l15][ks*32 + kg*8 + i] as bf16
    short8v Af[4];
    #pragma unroll
    for (int ks = 0; ks < 4; ++ks) {
        short8v af = {0, 0, 0, 0, 0, 0, 0, 0};
        if (aok) {
            const float4* p = (const float4*)(x + arow * DF + ks * 32 + kg * 8);
            float4 v0 = p[0], v1 = p[1];
            af[0] = (short)f2bf(v0.x); af[1] = (short)f2bf(v0.y);
            af[2] = (short)f2bf(v0.z); af[3] = (short)f2bf(v0.w);
            af[4] = (short)f2bf(v1.x); af[5] = (short)f2bf(v1.y);
            af[6] = (short)f2bf(v1.z); af[7] = (short)f2bf(v1.w);
        }
        Af[ks] = af;
    }

    #pragma unroll
    for (int ct = 0; ct < 8; ++ct) {
        f32x4 acc = {0.f, 0.f, 0.f, 0.f};
        #pragma unroll
        for (int ks = 0; ks < 4; ++ks) {
            // B-frag: lane holds Wc1[ks*32+kg*8+i][ct*16+l15] = Wc1T[(ct*16+l15)*128 + ks*32+kg*8 ..+7]
            short8v bf = *(const short8v*)(Wc1T + (ct * 16 + l15) * DF + ks * 32 + kg * 8);
            acc = __builtin_amdgcn_mfma_f32_16x16x32_bf16(Af[ks], bf, acc, 0, 0, 0);
        }
        // C/D: col = l15 (+ct*16), row = kg*4 + r
        #pragma unroll
        for (int r = 0; r < 4; ++r) {
            long row = r0w + kg * 4 + r;
            if (row < N_NODES)
                hb[row * NH + ct * 16 + l15] = f2bf(acc[r]);
        }
    }
}

// ---------------------------------------------------------------- K3a/b/c: parallel exclusive scan deg -> rowptr
__global__ __launch_bounds__(256) void scan_part_kernel(
    const int* __restrict__ deg, int* __restrict__ bsum)
{
    __shared__ int red[256];
    int t = threadIdx.x;
    int n = blockIdx.x * 256 + t;
    red[t] = (n < N_NODES) ? deg[n] : 0;
    __syncthreads();
    for (int o = 128; o > 0; o >>= 1) {
        if (t < o) red[t] += red[t + o];
        __syncthreads();
    }
    if (t == 0) bsum[blockIdx.x] = red[0];
}

__global__ __launch_bounds__(256) void scan_top_kernel(
    const int* __restrict__ bsum, int* __restrict__ boff)
{
    __shared__ int s[256];
    int t = threadIdx.x;
    s[t] = (t < SCAN_B) ? bsum[t] : 0;
    __syncthreads();
    for (int o = 1; o < 256; o <<= 1) {
        int v = (t >= o) ? s[t - o] : 0;
        __syncthreads();
        s[t] += v;
        __syncthreads();
    }
    if (t < SCAN_B) boff[t] = (t == 0) ? 0 : s[t - 1];
}

__global__ __launch_bounds__(256) void scan_write_kernel(
    const int* __restrict__ deg, const int* __restrict__ boff,
    int* __restrict__ rowptr)
{
    __shared__ int s[256];
    int t = threadIdx.x;
    int n = blockIdx.x * 256 + t;
    int v = (n < N_NODES) ? deg[n] : 0;
    s[t] = v;
    __syncthreads();
    for (int o = 1; o < 256; o <<= 1) {
        int u = (t >= o) ? s[t - o] : 0;
        __syncthreads();
        s[t] += u;
        __syncthreads();
    }
    if (n < N_NODES) rowptr[n] = boff[blockIdx.x] + s[t] - v;
}

// ---------------------------------------------------------------- K4: CSR fill, payload packed as int2{src, ew-bits}
__global__ __launch_bounds__(256) void fill_csr_kernel(
    const int* __restrict__ dst, const int* __restrict__ src,
    const float* __restrict__ ew, int* __restrict__ rowptr,
    int2* __restrict__ csr)
{
    int e = blockIdx.x * 256 + threadIdx.x;
    if (e >= N_EDGES) return;
    int p = atomicAdd(&rowptr[dst[e]], 1);
    csr[p] = make_int2(src[e], __float_as_int(ew[e]));
}

// ---------------------------------------------------------------- K5: fused gather1 + gemm2 (1 wave = 1 node, no LDS)
// Wave = 4 groups x 16 lanes. Group g takes edge j*4+g; lane l16 loads h cols l16*8..+7 (bf16x8, 16B).
__global__ __launch_bounds__(256) void gather1_gemm2_kernel(
    const unsigned short* __restrict__ hb, const int* __restrict__ rp_end,
    const int2* __restrict__ csr, const float* __restrict__ bc1,
    const float* __restrict__ Wc2, unsigned short* __restrict__ h2b)
{
    int t = threadIdx.x;
    int node = blockIdx.x * 4 + (t >> 6);   // grid 12500*4 = 50000 exact
    int lane = t & 63;
    int l16 = lane & 15, g = lane >> 4;

    int end   = rp_end[node];
    int start = (node == 0) ? 0 : rp_end[node - 1];

    float acc[8];
    #pragma unroll
    for (int i = 0; i < 8; ++i) acc[i] = 0.f;

    for (int base = start; base < end; base += 64) {
        int n = end - base; if (n > 64) n = 64;
        int s = 0; float w = 0.f;
        if (lane < n) {
            int2 p = csr[base + lane];
            s = p.x; w = __int_as_float(p.y);
        }
        #pragma unroll 4
        for (int j = 0; j * 4 < n; ++j) {
            int idx = j * 4 + g;
            int   sj = __shfl(s, idx, 64);
            float wj = __shfl(w, idx, 64);             // 0 beyond n -> no contribution
            short8v hv = *(const short8v*)(hb + (long)sj * NH + l16 * 8);
            #pragma unroll
            for (int i = 0; i < 8; ++i)
                acc[i] += wj * bf2f((unsigned short)hv[i]);
        }
    }
    #pragma unroll
    for (int i = 0; i < 8; ++i) {
        acc[i] += __shfl_xor(acc[i], 16, 64);
        acc[i] += __shfl_xor(acc[i], 32, 64);
    }
    float4 b0 = *(const float4*)(bc1 + l16 * 8);
    float4 b1 = *(const float4*)(bc1 + l16 * 8 + 4);
    float h1v[8];
    h1v[0] = fmaxf(acc[0] + b0.x, 0.f); h1v[1] = fmaxf(acc[1] + b0.y, 0.f);
    h1v[2] = fmaxf(acc[2] + b0.z, 0.f); h1v[3] = fmaxf(acc[3] + b0.w, 0.f);
    h1v[4] = fmaxf(acc[4] + b1.x, 0.f); h1v[5] = fmaxf(acc[5] + b1.y, 0.f);
    h1v[6] = fmaxf(acc[6] + b1.z, 0.f); h1v[7] = fmaxf(acc[7] + b1.w, 0.f);

    // gemm2 in registers: h1[k] lives in lane (k>>3), elem (k&7). Wc2 is L1-resident.
    int c = (lane < NC) ? lane : (NC - 1);
    float o = 0.f;
    #pragma unroll 8
    for (int k = 0; k < NH; ++k) {
        float hk = __shfl(h1v[k & 7], k >> 3, 64);     // uniform src lane -> broadcast
        o += hk * Wc2[k * NC + c];
    }
    if (lane < NC)
        h2b[(long)node * NC + lane] = f2bf(o);         // 80B/row contiguous
}

// ---------------------------------------------------------------- K6: gather2 + bias + (-log_softmax) (1 wave = 1 node)
// h2b rows are 40 bf16 (80B) -> table is 4.0 MB (per-XCD-L2 sized). Lanes l16<10 load 8B each.
__global__ __launch_bounds__(256) void gather2_lsm_kernel(
    const unsigned short* __restrict__ h2b, const int* __restrict__ rp_end,
    const int2* __restrict__ csr, const float* __restrict__ bc2,
    float* __restrict__ out)
{
    int t = threadIdx.x;
    int node = blockIdx.x * 4 + (t >> 6);
    int lane = t & 63;
    int l16 = lane & 15, g = lane >> 4;
    bool valid = (l16 < 10);

    int end   = rp_end[node];
    int start = (node == 0) ? 0 : rp_end[node - 1];

    float acc[4];
    #pragma unroll
    for (int i = 0; i < 4; ++i) acc[i] = 0.f;

    for (int base = start; base < end; base += 64) {
        int n = end - base; if (n > 64) n = 64;
        int s = 0; float w = 0.f;
        if (lane < n) {
            int2 p = csr[base + lane];
            s = p.x; w = __int_as_float(p.y);
        }
        #pragma unroll 4
        for (int j = 0; j * 4 < n; ++j) {
            int idx = j * 4 + g;
            int   sj = __shfl(s, idx, 64);
            float wj = __shfl(w, idx, 64);
            if (valid) {
                short4v hv = *(const short4v*)(h2b + (long)sj * NC + l16 * 4);
                #pragma unroll
                for (int i = 0; i < 4; ++i)
                    acc[i] += wj * bf2f((unsigned short)hv[i]);
            }
        }
    }
    #pragma unroll
    for (int i = 0; i < 4; ++i) {
        acc[i] += __shfl_xor(acc[i], 16, 64);
        acc[i] += __shfl_xor(acc[i], 32, 64);
    }

    float4 bcv = valid ? *(const float4*)(bc2 + l16 * 4) : make_float4(0.f, 0.f, 0.f, 0.f);
    float v[4];
    v[0] = acc[0] + bcv.x; v[1] = acc[1] + bcv.y;
    v[2] = acc[2] + bcv.z; v[3] = acc[3] + bcv.w;

    float mx = valid ? fmaxf(fmaxf(v[0], v[1]), fmaxf(v[2], v[3])) : -INFINITY;
    #pragma unroll
    for (int o = 1; o <= 8; o <<= 1) mx = fmaxf(mx, __shfl_xor(mx, o, 64));
    float se = 0.f;
    if (valid) se = expf(v[0]-mx) + expf(v[1]-mx) + expf(v[2]-mx) + expf(v[3]-mx);
    #pragma unroll
    for (int o = 1; o <= 8; o <<= 1) se += __shfl_xor(se, o, 64);
    float lse = mx + logf(se);

    if (valid && g == 0) {
        float4 r = make_float4(lse - v[0], lse - v[1], lse - v[2], lse - v[3]);
        *(float4*)(out + (long)node * NC + l16 * 4) = r;
    }
}

// ----------------------------------------------------------------
extern "C" void kernel_launch(void* const* d_in, const int* in_sizes, int n_in,
                              void* d_out, int out_size, void* d_ws, size_t ws_size,
                              hipStream_t stream)
{
    const float* x         = (const float*)d_in[0];
    const float* edge_feat = (const float*)d_in[1];
    const float* W1        = (const float*)d_in[2];
    const float* b1        = (const float*)d_in[3];
    const float* W2        = (const float*)d_in[4];
    const float* b2        = (const float*)d_in[5];
    const float* Wc1       = (const float*)d_in[6];
    const float* bc1       = (const float*)d_in[7];
    const float* Wc2       = (const float*)d_in[8];
    const float* bc2       = (const float*)d_in[9];
    const int*   eidx      = (const int*)d_in[10];
    const int*   dst = eidx;             // edge_index[0] (aggregation target)
    const int*   src = eidx + N_EDGES;   // edge_index[1]
    float* out = (float*)d_out;

    // ws layout: ew | hb(bf16) | h2b(bf16,40 cols) | csr(int2) | deg | rowptr | bsum | boff | Wc1T
    float*          ew     = (float*)d_ws;                       // E        3.2 MB
    unsigned short* hb     = (unsigned short*)(ew + N_EDGES);    // N*NH*2  12.8 MB
    unsigned short* h2b    = hb + (long)N_NODES * NH;            // N*NC*2   4.0 MB
    int2*           csr    = (int2*)(h2b + (long)N_NODES * NC);  // E*8      6.4 MB
    int*            deg    = (int*)(csr + N_EDGES);              // N        0.2 MB
    int*            rowptr = deg + N_NODES;                      // N        0.2 MB
    int*            bsum   = rowptr + N_NODES;                   // 256
    int*            boff   = bsum + 256;                         // 256
    unsigned short* Wc1T   = (unsigned short*)(boff + 256);      // 128*128  32 KB

    hipMemsetAsync(deg, 0, sizeof(int) * (size_t)N_NODES, stream);

    wc1t_kernel<<<64, 256, 0, stream>>>(Wc1, Wc1T);
    edge_mlp_kernel<<<N_EDGES / 256, 256, 0, stream>>>(
        edge_feat, W1, b1, W2, b2, dst, ew, deg);
    gemm1_kernel<<<(N_NODES + 63) / 64, 256, 0, stream>>>(x, Wc1T, hb);
    scan_part_kernel<<<SCAN_B, 256, 0, stream>>>(deg, bsum);
    scan_top_kernel<<<1, 256, 0, stream>>>(bsum, boff);
    scan_write_kernel<<<SCAN_B, 256, 0, stream>>>(deg, boff, rowptr);
    fill_csr_kernel<<<(N_EDGES + 255) / 256, 256, 0, stream>>>(
        dst, src, ew, rowptr, csr);
    gather1_gemm2_kernel<<<N_NODES / 4, 256, 0, stream>>>(
        hb, rowptr, csr, bc1, Wc2, h2b);
    gather2_lsm_kernel<<<N_NODES / 4, 256, 0, stream>>>(
        h2b, rowptr, csr, bc2, out);
}